// Round 4
// baseline (195.729 us; speedup 1.0000x reference)
//
#include <hip/hip_runtime.h>
#include <hip/hip_bf16.h>

#define BATCH  2
#define SEQ    2048
#define DMODEL 1024
#define NHEAD  16
#define DHEAD  64
#define NTOK   (BATCH * SEQ)

using f32x4 = __attribute__((ext_vector_type(4))) float;
using s16x4 = __attribute__((ext_vector_type(4))) short;
using s16x8 = __attribute__((ext_vector_type(8))) short;

__device__ __forceinline__ short f2bf(float f) {
  __hip_bfloat16 h = __float2bfloat16(f);   // RNE; backend emits cvt_pk pairs
  return *(short*)&h;
}

__device__ __forceinline__ void gload_lds16(const short* g, short* l) {
  __builtin_amdgcn_global_load_lds(
      (const __attribute__((address_space(1))) void*)g,
      (__attribute__((address_space(3))) void*)l, 16, 0, 0);
}

// ---------------------------------------------------------------------------
// Transpose + cast all 4 weights: W[k][n] fp32 -> Wt[n][k] bf16
// ---------------------------------------------------------------------------
__global__ __launch_bounds__(256) void wtrans_kernel(
    const float* __restrict__ Wq, const float* __restrict__ Wk,
    const float* __restrict__ Wv, const float* __restrict__ Wo,
    short* __restrict__ Wt) {
  __shared__ short tile[64][72];
  const float* W = blockIdx.z == 0 ? Wq : blockIdx.z == 1 ? Wk
                 : blockIdx.z == 2 ? Wv : Wo;
  short* out = Wt + (size_t)blockIdx.z * DMODEL * DMODEL;
  int k0 = blockIdx.x * 64, n0 = blockIdx.y * 64;
  int t = threadIdx.x;
#pragma unroll
  for (int i = 0; i < 4; ++i) {
    int idx = t + i * 256;
    int row = idx >> 4, c4 = idx & 15;
    f32x4 v = *(const f32x4*)(W + (size_t)(k0 + row) * DMODEL + n0 + c4 * 4);
    s16x4 p;
    p[0] = f2bf(v[0]); p[1] = f2bf(v[1]); p[2] = f2bf(v[2]); p[3] = f2bf(v[3]);
    *(s16x4*)&tile[row][c4 * 4] = p;
  }
  __syncthreads();
#pragma unroll
  for (int i = 0; i < 2; ++i) {
    int idx = t + i * 256;
    int nrow = idx >> 3, c8 = idx & 7;
    s16x8 p;
#pragma unroll
    for (int j = 0; j < 8; ++j) p[j] = tile[c8 * 8 + j][nrow];
    *(s16x8*)(out + (size_t)(n0 + nrow) * DMODEL + k0 + c8 * 8) = p;
  }
}

// ---------------------------------------------------------------------------
// Pack mask int32 -> bit words: Mp[b*SEQ+q][kt] bit j = mask[b][q][kt*64+j]
// ---------------------------------------------------------------------------
__global__ __launch_bounds__(256) void mpack_kernel(
    const int* __restrict__ mask, unsigned long long* __restrict__ Mp) {
  const int total_words = BATCH * SEQ * (SEQ / 64);   // 131072
  int lane = threadIdx.x & 63;
  int wv = blockIdx.x * 4 + (threadIdx.x >> 6);
  int nw = gridDim.x * 4;
  for (int w = wv; w < total_words; w += nw) {
    int mv = mask[(size_t)w * 64 + lane];
    unsigned long long bits = __ballot(mv != 0);
    if (lane == 0) Mp[w] = bits;
  }
}

// ---------------------------------------------------------------------------
// QKV projection: X fp32 @ Wt^T + b -> bf16 [b*H+h][s][d]
// A: fp32 load + cvt staging. B: global_load_lds(16B) direct to LDS.
// Q pre-scaled by (1/8)*log2(e).  grid (32,8,3), block 256.
// ---------------------------------------------------------------------------
__global__ __launch_bounds__(256) void proj_qkv_kernel(
    const float* __restrict__ Xq, const float* __restrict__ Xk,
    const float* __restrict__ Xv, const short* __restrict__ Wt,
    const float* __restrict__ bq, const float* __restrict__ bk,
    const float* __restrict__ bv, short* __restrict__ QKV) {
  __shared__ short As[128][32];   // linear, 8KB
  __shared__ short Bs[128][32];   // linear, 8KB (glLDS dest: no padding)
  const int sel = blockIdx.z;
  const float* X    = sel == 0 ? Xq : sel == 1 ? Xk : Xv;
  const float* bias = sel == 0 ? bq : sel == 1 ? bk : bv;
  const short* Wsel = Wt + (size_t)sel * DMODEL * DMODEL;
  short* Obuf = QKV + (size_t)sel * ((size_t)BATCH * NHEAD * SEQ * DHEAD);
  const float scale = sel == 0 ? 0.18033688011111793f : 1.0f;  // (1/8)*log2e

  int m0 = blockIdx.x * 128, n0 = blockIdx.y * 128;
  int t = threadIdx.x, wid = t >> 6, lane = t & 63;
  int lr = lane & 15, lg = lane >> 4;
  int wr = wid >> 1, wc = wid & 1;
  f32x4 acc[4][4] = {};

  for (int kt = 0; kt < DMODEL / 32; ++kt) {
    int k0 = kt * 32;
    __syncthreads();
    // B: 128x32 bf16 = 8KB via global_load_lds, 2 chunks/thread
#pragma unroll
    for (int i = 0; i < 2; ++i) {
      int c = i * 256 + t;
      short* lbase = &Bs[0][0] + (size_t)((i * 256 + (t & ~63)) << 3);
      gload_lds16(Wsel + (size_t)(n0 + (c >> 2)) * DMODEL + k0 + ((c & 3) << 3),
                  lbase);
    }
    // A: 128x32 fp32 -> bf16 (2x f32x4 loads + 1 ds_write_b128 per iter)
#pragma unroll
    for (int i = 0; i < 2; ++i) {
      int idx = t + i * 256, row = idx >> 2, c8 = idx & 3;
      const float* src = X + (size_t)(m0 + row) * DMODEL + k0 + c8 * 8;
      f32x4 v0 = *(const f32x4*)src;
      f32x4 v1 = *(const f32x4*)(src + 4);
      s16x8 p;
      p[0] = f2bf(v0[0]); p[1] = f2bf(v0[1]); p[2] = f2bf(v0[2]); p[3] = f2bf(v0[3]);
      p[4] = f2bf(v1[0]); p[5] = f2bf(v1[1]); p[6] = f2bf(v1[2]); p[7] = f2bf(v1[3]);
      *(s16x8*)&As[row][c8 * 8] = p;
    }
    __syncthreads();
    s16x8 afr[4], bfr[4];
#pragma unroll
    for (int mi = 0; mi < 4; ++mi)
      afr[mi] = *(const s16x8*)&As[wr * 64 + mi * 16 + lr][lg * 8];
#pragma unroll
    for (int ni = 0; ni < 4; ++ni)
      bfr[ni] = *(const s16x8*)&Bs[wc * 64 + ni * 16 + lr][lg * 8];
#pragma unroll
    for (int mi = 0; mi < 4; ++mi)
#pragma unroll
      for (int ni = 0; ni < 4; ++ni)
        acc[mi][ni] = __builtin_amdgcn_mfma_f32_16x16x32_bf16(
            afr[mi], bfr[ni], acc[mi][ni], 0, 0, 0);
  }
#pragma unroll
  for (int mi = 0; mi < 4; ++mi)
#pragma unroll
    for (int ni = 0; ni < 4; ++ni) {
      int n = n0 + wc * 64 + ni * 16 + lr;
      float bv_ = bias[n];
      int h = n >> 6, d = n & 63;
#pragma unroll
      for (int r = 0; r < 4; ++r) {
        int m = m0 + wr * 64 + mi * 16 + lg * 4 + r;
        int b = m >> 11, s = m & (SEQ - 1);
        float val = (acc[mi][ni][r] + bv_) * scale;
        Obuf[((size_t)(b * NHEAD + h) * SEQ + s) * DHEAD + d] = f2bf(val);
      }
    }
}

// ---------------------------------------------------------------------------
// Flash attention, swapped QK^T. grid (32, 32), block 256.
// XOR-swizzled LDS (conflict-free) + async reg-staged K/V (T14) + setprio.
// ---------------------------------------------------------------------------
__global__ __launch_bounds__(256) void attn_kernel(
    const short* __restrict__ Qb, const short* __restrict__ Kb,
    const short* __restrict__ Vb, const unsigned long long* __restrict__ Mp,
    short* __restrict__ Ctx) {
  __shared__ short Ks[64 * 64];       // [key][d], 16B-chunk c ^= key&7
  __shared__ short Vt[64 * 64];       // [d][key], chunk c ^= d&7
  __shared__ short Ps[4 * 16 * 64];   // per-wave [q][key], chunk c ^= q&7
  int qt = blockIdx.x, bh = blockIdx.y;
  int b = bh >> 4, h = bh & 15;
  int q0 = qt * 64;
  int t = threadIdx.x, wid = t >> 6, lane = t & 63;
  int lr = lane & 15, lg = lane >> 4;
  int lr7 = lr & 7;

  const short* Qrow = Qb + ((size_t)bh * SEQ + q0 + wid * 16 + lr) * DHEAD;
  s16x8 qf[2];
  qf[0] = *(const s16x8*)(Qrow + lg * 8);
  qf[1] = *(const s16x8*)(Qrow + 32 + lg * 8);

  const short* KbBase = Kb + (size_t)bh * SEQ * DHEAD;
  const short* VbBase = Vb + (size_t)bh * SEQ * DHEAD;

  float m_run = -1e30f, l_run = 0.f;   // per-lane, q = lr
  f32x4 o_acc[4] = {};

  const unsigned long long* mrow =
      Mp + ((size_t)b * SEQ + q0 + wid * 16 + lr) * (SEQ / 64);
  unsigned long long mw = mrow[0];

  // prologue: stage tile 0 into regs
  s16x8 kreg[2], vreg[2];
#pragma unroll
  for (int i = 0; i < 2; ++i) {
    kreg[i] = *(const s16x8*)(KbBase + (size_t)((t >> 3) + i * 32) * DHEAD + (t & 7) * 8);
    vreg[i] = *(const s16x8*)(VbBase + (size_t)lane * DHEAD + (wid + i * 4) * 8);
  }

  for (int kt = 0; kt < SEQ / 64; ++kt) {
    unsigned long long mw_cur = mw;
    __syncthreads();   // prev tile's LDS reads done
    // write staged regs -> LDS (swizzled)
#pragma unroll
    for (int i = 0; i < 2; ++i) {
      int krow = (t >> 3) + i * 32, kc = t & 7;
      *(s16x8*)&Ks[krow * 64 + ((kc ^ (krow & 7)) << 3)] = kreg[i];
      int vc8 = wid + i * 4;
#pragma unroll
      for (int j = 0; j < 8; ++j) {
        int d = vc8 * 8 + j;
        Vt[d * 64 + ((((lane >> 3) ^ (d & 7)) << 3) | (lane & 7))] = vreg[i][j];
      }
    }
    __syncthreads();
    // issue next tile's loads (in flight across compute — T14)
    if (kt + 1 < SEQ / 64) {
      int k0n = (kt + 1) * 64;
#pragma unroll
      for (int i = 0; i < 2; ++i) {
        kreg[i] = *(const s16x8*)(KbBase + (size_t)(k0n + (t >> 3) + i * 32) * DHEAD + (t & 7) * 8);
        vreg[i] = *(const s16x8*)(VbBase + (size_t)(k0n + lane) * DHEAD + (wid + i * 4) * 8);
      }
      mw = mrow[kt + 1];
    }

    // S^T = K·Q^T : sfr[nf][r] = S[key = nf*16 + lg*4 + r][q = lr]
    f32x4 sfr[4];
    __builtin_amdgcn_s_setprio(1);
#pragma unroll
    for (int nf = 0; nf < 4; ++nf) {
      int row = nf * 16 + lr;
      s16x8 kf0 = *(const s16x8*)&Ks[row * 64 + ((lg ^ lr7) << 3)];
      s16x8 kf1 = *(const s16x8*)&Ks[row * 64 + (((4 + lg) ^ lr7) << 3)];
      f32x4 c = {};
      c = __builtin_amdgcn_mfma_f32_16x16x32_bf16(kf0, qf[0], c, 0, 0, 0);
      c = __builtin_amdgcn_mfma_f32_16x16x32_bf16(kf1, qf[1], c, 0, 0, 0);
      sfr[nf] = c;
    }
    __builtin_amdgcn_s_setprio(0);

    unsigned w0 = (unsigned)(mw_cur >> (lg * 4));
    unsigned w1 = (unsigned)(mw_cur >> (lg * 4 + 32));
#pragma unroll
    for (int nf = 0; nf < 4; ++nf)
#pragma unroll
      for (int r = 0; r < 4; ++r) {
        unsigned bit = (nf < 2) ? (w0 >> (nf * 16 + r)) : (w1 >> ((nf - 2) * 16 + r));
        if (bit & 1u) sfr[nf][r] = -1e30f;
      }
    float tm = fmaxf(fmaxf(fmaxf(sfr[0][0], sfr[0][1]), fmaxf(sfr[0][2], sfr[0][3])),
                     fmaxf(fmaxf(sfr[1][0], sfr[1][1]), fmaxf(sfr[1][2], sfr[1][3])));
    float tm2 = fmaxf(fmaxf(fmaxf(sfr[2][0], sfr[2][1]), fmaxf(sfr[2][2], sfr[2][3])),
                      fmaxf(fmaxf(sfr[3][0], sfr[3][1]), fmaxf(sfr[3][2], sfr[3][3])));
    tm = fmaxf(tm, tm2);
    tm = fmaxf(tm, __shfl_xor(tm, 16, 64));
    tm = fmaxf(tm, __shfl_xor(tm, 32, 64));

    bool small = __all(tm <= m_run + 8.0f);
    if (!small) {
      float mnew = fmaxf(m_run, tm);
      float scl = __builtin_amdgcn_exp2f(m_run - mnew);
      m_run = mnew;
      l_run *= scl;
      float scl_o[4];
#pragma unroll
      for (int r = 0; r < 4; ++r) scl_o[r] = __shfl(scl, lg * 4 + r, 64);
#pragma unroll
      for (int nf = 0; nf < 4; ++nf)
#pragma unroll
        for (int r = 0; r < 4; ++r) o_acc[nf][r] *= scl_o[r];
    }
    float ps4[4];
#pragma unroll
    for (int nf = 0; nf < 4; ++nf) {
#pragma unroll
      for (int r = 0; r < 4; ++r)
        sfr[nf][r] = __builtin_amdgcn_exp2f(sfr[nf][r] - m_run);
      ps4[nf] = (sfr[nf][0] + sfr[nf][1]) + (sfr[nf][2] + sfr[nf][3]);
    }
    float ps = (ps4[0] + ps4[1]) + (ps4[2] + ps4[3]);
    ps += __shfl_xor(ps, 16, 64);
    ps += __shfl_xor(ps, 32, 64);
    l_run += ps;

    // P -> LDS (wave-private, swizzled), 4 x ds_write_b64
    int psbase = wid * (16 * 64) + lr * 64;
#pragma unroll
    for (int nf = 0; nf < 4; ++nf) {
      s16x4 pk;
#pragma unroll
      for (int r = 0; r < 4; ++r) pk[r] = f2bf(sfr[nf][r]);
      *(s16x4*)&Ps[psbase + ((((2 * nf + (lg >> 1)) ^ lr7) << 3) | ((lg & 1) << 2))] = pk;
    }
    asm volatile("s_waitcnt lgkmcnt(0)" ::: "memory");
    __builtin_amdgcn_sched_barrier(0);

    // PV: O += P·V
    __builtin_amdgcn_s_setprio(1);
#pragma unroll
    for (int ks = 0; ks < 2; ++ks) {
      s16x8 pf = *(const s16x8*)&Ps[psbase + (((ks * 4 + lg) ^ lr7) << 3)];
#pragma unroll
      for (int nf = 0; nf < 4; ++nf) {
        int d = nf * 16 + lr;
        s16x8 vf = *(const s16x8*)&Vt[d * 64 + (((ks * 4 + lg) ^ lr7) << 3)];
        o_acc[nf] = __builtin_amdgcn_mfma_f32_16x16x32_bf16(pf, vf, o_acc[nf], 0, 0, 0);
      }
    }
    __builtin_amdgcn_s_setprio(0);
  }
  // epilogue: o_acc[nf][r] is q = lg*4+r, d = nf*16+lr
  float l_o[4];
#pragma unroll
  for (int r = 0; r < 4; ++r) l_o[r] = __shfl(l_run, lg * 4 + r, 64);
#pragma unroll
  for (int nf = 0; nf < 4; ++nf)
#pragma unroll
    for (int r = 0; r < 4; ++r) {
      int srow = q0 + wid * 16 + lg * 4 + r;
      float val = o_acc[nf][r] / l_o[r];
      Ctx[((size_t)b * SEQ + srow) * DMODEL + h * DHEAD + nf * 16 + lr] = f2bf(val);
    }
}

// ---------------------------------------------------------------------------
// Output projection: ctx bf16 @ Wo + bo -> fp32 out.  Full m97 structure:
// both operands staged via global_load_lds.  grid (32,8), block 256.
// ---------------------------------------------------------------------------
__global__ __launch_bounds__(256) void proj_out_kernel(
    const short* __restrict__ Ctx, const short* __restrict__ Wot,
    const float* __restrict__ bo, float* __restrict__ Out) {
  __shared__ short As[128][32];
  __shared__ short Bs[128][32];
  int m0 = blockIdx.x * 128, n0 = blockIdx.y * 128;
  int t = threadIdx.x, wid = t >> 6, lane = t & 63;
  int lr = lane & 15, lg = lane >> 4;
  int wr = wid >> 1, wc = wid & 1;
  f32x4 acc[4][4] = {};

  for (int kt = 0; kt < DMODEL / 32; ++kt) {
    int k0 = kt * 32;
    __syncthreads();
#pragma unroll
    for (int i = 0; i < 2; ++i) {
      int c = i * 256 + t;
      size_t lofs = (size_t)((i * 256 + (t & ~63)) << 3);
      gload_lds16(Ctx + (size_t)(m0 + (c >> 2)) * DMODEL + k0 + ((c & 3) << 3),
                  &As[0][0] + lofs);
      gload_lds16(Wot + (size_t)(n0 + (c >> 2)) * DMODEL + k0 + ((c & 3) << 3),
                  &Bs[0][0] + lofs);
    }
    __syncthreads();
    s16x8 afr[4], bfr[4];
#pragma unroll
    for (int mi = 0; mi < 4; ++mi)
      afr[mi] = *(const s16x8*)&As[wr * 64 + mi * 16 + lr][lg * 8];
#pragma unroll
    for (int ni = 0; ni < 4; ++ni)
      bfr[ni] = *(const s16x8*)&Bs[wc * 64 + ni * 16 + lr][lg * 8];
#pragma unroll
    for (int mi = 0; mi < 4; ++mi)
#pragma unroll
      for (int ni = 0; ni < 4; ++ni)
        acc[mi][ni] = __builtin_amdgcn_mfma_f32_16x16x32_bf16(
            afr[mi], bfr[ni], acc[mi][ni], 0, 0, 0);
  }
#pragma unroll
  for (int mi = 0; mi < 4; ++mi)
#pragma unroll
    for (int ni = 0; ni < 4; ++ni) {
      int n = n0 + wc * 64 + ni * 16 + lr;
      float bv_ = bo[n];
#pragma unroll
      for (int r = 0; r < 4; ++r) {
        int m = m0 + wr * 64 + mi * 16 + lg * 4 + r;
        Out[(size_t)m * DMODEL + n] = acc[mi][ni][r] + bv_;
      }
    }
}

// ---------------------------------------------------------------------------
extern "C" void kernel_launch(void* const* d_in, const int* in_sizes, int n_in,
                              void* d_out, int out_size, void* d_ws, size_t ws_size,
                              hipStream_t stream) {
  const float* key_in   = (const float*)d_in[0];
  const float* value_in = (const float*)d_in[1];
  const float* query_in = (const float*)d_in[2];
  const int*   mask     = (const int*)d_in[3];
  const float* Wq = (const float*)d_in[4];
  const float* bq = (const float*)d_in[5];
  const float* Wk = (const float*)d_in[6];
  const float* bk = (const float*)d_in[7];
  const float* Wv = (const float*)d_in[8];
  const float* bv = (const float*)d_in[9];
  const float* Wo = (const float*)d_in[10];
  const float* bo = (const float*)d_in[11];
  float* out = (float*)d_out;

  short* ws = (short*)d_ws;
  const size_t WSZ   = (size_t)DMODEL * DMODEL;
  const size_t QKVSZ = (size_t)BATCH * NHEAD * SEQ * DHEAD;
  short* Wt  = ws;                         // [4][1024][1024] bf16
  short* QKV = ws + 4 * WSZ;
  short* Qb  = QKV;
  short* Kb  = QKV + QKVSZ;
  short* Vb  = QKV + 2 * QKVSZ;
  short* Ctx = QKV + 3 * QKVSZ;
  // Mp overlays the Wq-transposed region (1 MB < 2 MB), written AFTER
  // proj_qkv has consumed Wt[0] (stream-serialized).
  unsigned long long* Mp = (unsigned long long*)ws;

  wtrans_kernel<<<dim3(16, 16, 4), 256, 0, stream>>>(Wq, Wk, Wv, Wo, Wt);
  proj_qkv_kernel<<<dim3(32, 8, 3), 256, 0, stream>>>(
      query_in, key_in, value_in, Wt, bq, bk, bv, QKV);
  mpack_kernel<<<dim3(1024), 256, 0, stream>>>(mask, Mp);
  attn_kernel<<<dim3(32, 32), 256, 0, stream>>>(Qb, Kb, Vb, Mp, Ctx);
  proj_out_kernel<<<dim3(32, 8), 256, 0, stream>>>(Ctx, Wt + 3 * WSZ, bo, out);
}

// Round 5
// 185.078 us; speedup vs baseline: 1.0575x; 1.0575x over previous
//
#include <hip/hip_runtime.h>
#include <hip/hip_bf16.h>

#define BATCH  2
#define SEQ    2048
#define DMODEL 1024
#define NHEAD  16
#define DHEAD  64
#define NTOK   (BATCH * SEQ)

using f32x4 = __attribute__((ext_vector_type(4))) float;
using s16x4 = __attribute__((ext_vector_type(4))) short;
using s16x8 = __attribute__((ext_vector_type(8))) short;

__device__ __forceinline__ short f2bf(float f) {
  __hip_bfloat16 h = __float2bfloat16(f);   // RNE; backend emits cvt_pk pairs
  return *(short*)&h;
}

__device__ __forceinline__ void gload_lds16(const short* g, short* l) {
  __builtin_amdgcn_global_load_lds(
      (const __attribute__((address_space(1))) void*)g,
      (__attribute__((address_space(3))) void*)l, 16, 0, 0);
}

// ---------------------------------------------------------------------------
// Transpose + cast all 4 weights: W[k][n] fp32 -> Wt[n][k] bf16
// ---------------------------------------------------------------------------
__global__ __launch_bounds__(256) void wtrans_kernel(
    const float* __restrict__ Wq, const float* __restrict__ Wk,
    const float* __restrict__ Wv, const float* __restrict__ Wo,
    short* __restrict__ Wt) {
  __shared__ short tile[64][72];
  const float* W = blockIdx.z == 0 ? Wq : blockIdx.z == 1 ? Wk
                 : blockIdx.z == 2 ? Wv : Wo;
  short* out = Wt + (size_t)blockIdx.z * DMODEL * DMODEL;
  int k0 = blockIdx.x * 64, n0 = blockIdx.y * 64;
  int t = threadIdx.x;
#pragma unroll
  for (int i = 0; i < 4; ++i) {
    int idx = t + i * 256;
    int row = idx >> 4, c4 = idx & 15;
    f32x4 v = *(const f32x4*)(W + (size_t)(k0 + row) * DMODEL + n0 + c4 * 4);
    s16x4 p;
    p[0] = f2bf(v[0]); p[1] = f2bf(v[1]); p[2] = f2bf(v[2]); p[3] = f2bf(v[3]);
    *(s16x4*)&tile[row][c4 * 4] = p;
  }
  __syncthreads();
#pragma unroll
  for (int i = 0; i < 2; ++i) {
    int idx = t + i * 256;
    int nrow = idx >> 3, c8 = idx & 7;
    s16x8 p;
#pragma unroll
    for (int j = 0; j < 8; ++j) p[j] = tile[c8 * 8 + j][nrow];
    *(s16x8*)(out + (size_t)(n0 + nrow) * DMODEL + k0 + c8 * 8) = p;
  }
}

// ---------------------------------------------------------------------------
// Pack mask int32 -> bit words: Mp[b*SEQ+q][kt] bit j = mask[b][q][kt*64+j]
// ---------------------------------------------------------------------------
__global__ __launch_bounds__(256) void mpack_kernel(
    const int* __restrict__ mask, unsigned long long* __restrict__ Mp) {
  const int total_words = BATCH * SEQ * (SEQ / 64);   // 131072
  int lane = threadIdx.x & 63;
  int wv = blockIdx.x * 4 + (threadIdx.x >> 6);
  int nw = gridDim.x * 4;
  for (int w = wv; w < total_words; w += nw) {
    int mv = mask[(size_t)w * 64 + lane];
    unsigned long long bits = __ballot(mv != 0);
    if (lane == 0) Mp[w] = bits;
  }
}

// ---------------------------------------------------------------------------
// QKV projection: X fp32 @ Wt^T + b -> bf16.
// Q,K -> [b*H+h][s][d] (Q pre-scaled by (1/8)*log2e); V -> [b*H+h][d][s].
// grid (32,8,3), block 256.
// ---------------------------------------------------------------------------
__global__ __launch_bounds__(256) void proj_qkv_kernel(
    const float* __restrict__ Xq, const float* __restrict__ Xk,
    const float* __restrict__ Xv, const short* __restrict__ Wt,
    const float* __restrict__ bq, const float* __restrict__ bk,
    const float* __restrict__ bv, short* __restrict__ QKV) {
  __shared__ short As[128][32];   // linear, 8KB
  __shared__ short Bs[128][32];   // linear, 8KB (glLDS dest: no padding)
  const int sel = blockIdx.z;
  const float* X    = sel == 0 ? Xq : sel == 1 ? Xk : Xv;
  const float* bias = sel == 0 ? bq : sel == 1 ? bk : bv;
  const short* Wsel = Wt + (size_t)sel * DMODEL * DMODEL;
  short* Obuf = QKV + (size_t)sel * ((size_t)BATCH * NHEAD * SEQ * DHEAD);
  const float scale = sel == 0 ? 0.18033688011111793f : 1.0f;  // (1/8)*log2e

  int m0 = blockIdx.x * 128, n0 = blockIdx.y * 128;
  int t = threadIdx.x, wid = t >> 6, lane = t & 63;
  int lr = lane & 15, lg = lane >> 4;
  int wr = wid >> 1, wc = wid & 1;
  f32x4 acc[4][4] = {};

  for (int kt = 0; kt < DMODEL / 32; ++kt) {
    int k0 = kt * 32;
    __syncthreads();
    // B: 128x32 bf16 = 8KB via global_load_lds, 2 chunks/thread
#pragma unroll
    for (int i = 0; i < 2; ++i) {
      int c = i * 256 + t;
      short* lbase = &Bs[0][0] + (size_t)((i * 256 + (t & ~63)) << 3);
      gload_lds16(Wsel + (size_t)(n0 + (c >> 2)) * DMODEL + k0 + ((c & 3) << 3),
                  lbase);
    }
    // A: 128x32 fp32 -> bf16 (2x f32x4 loads + 1 ds_write_b128 per iter)
#pragma unroll
    for (int i = 0; i < 2; ++i) {
      int idx = t + i * 256, row = idx >> 2, c8 = idx & 3;
      const float* src = X + (size_t)(m0 + row) * DMODEL + k0 + c8 * 8;
      f32x4 v0 = *(const f32x4*)src;
      f32x4 v1 = *(const f32x4*)(src + 4);
      s16x8 p;
      p[0] = f2bf(v0[0]); p[1] = f2bf(v0[1]); p[2] = f2bf(v0[2]); p[3] = f2bf(v0[3]);
      p[4] = f2bf(v1[0]); p[5] = f2bf(v1[1]); p[6] = f2bf(v1[2]); p[7] = f2bf(v1[3]);
      *(s16x8*)&As[row][c8 * 8] = p;
    }
    __syncthreads();
    s16x8 afr[4], bfr[4];
#pragma unroll
    for (int mi = 0; mi < 4; ++mi)
      afr[mi] = *(const s16x8*)&As[wr * 64 + mi * 16 + lr][lg * 8];
#pragma unroll
    for (int ni = 0; ni < 4; ++ni)
      bfr[ni] = *(const s16x8*)&Bs[wc * 64 + ni * 16 + lr][lg * 8];
#pragma unroll
    for (int mi = 0; mi < 4; ++mi)
#pragma unroll
      for (int ni = 0; ni < 4; ++ni)
        acc[mi][ni] = __builtin_amdgcn_mfma_f32_16x16x32_bf16(
            afr[mi], bfr[ni], acc[mi][ni], 0, 0, 0);
  }
  if (sel == 2) {
    // V^T layout: Obuf[(b*H+h)*64 + d][s]; r spans 4 consecutive s -> b64 store
    int bq_ = m0 >> 11;
    int s0 = (m0 & (SEQ - 1)) + wr * 64 + lg * 4;
#pragma unroll
    for (int mi = 0; mi < 4; ++mi)
#pragma unroll
      for (int ni = 0; ni < 4; ++ni) {
        int n = n0 + wc * 64 + ni * 16 + lr;
        float bv_ = bias[n];
        int h = n >> 6, d = n & 63;
        s16x4 pk;
#pragma unroll
        for (int r = 0; r < 4; ++r) pk[r] = f2bf(acc[mi][ni][r] + bv_);
        *(s16x4*)&Obuf[((size_t)(bq_ * NHEAD + h) * DHEAD + d) * SEQ
                       + s0 + mi * 16] = pk;
      }
  } else {
#pragma unroll
    for (int mi = 0; mi < 4; ++mi)
#pragma unroll
      for (int ni = 0; ni < 4; ++ni) {
        int n = n0 + wc * 64 + ni * 16 + lr;
        float bv_ = bias[n];
        int h = n >> 6, d = n & 63;
#pragma unroll
        for (int r = 0; r < 4; ++r) {
          int m = m0 + wr * 64 + mi * 16 + lg * 4 + r;
          int b = m >> 11, s = m & (SEQ - 1);
          float val = (acc[mi][ni][r] + bv_) * scale;
          Obuf[((size_t)(b * NHEAD + h) * SEQ + s) * DHEAD + d] = f2bf(val);
        }
      }
  }
}

// ---------------------------------------------------------------------------
// Flash attention, swapped QK^T. grid (32, 32), block 256.
// K,V^T staged via global_load_lds (pre-swizzled source), double-buffered,
// ONE barrier per KV-tile (T3-min).  Base-2 softmax domain.
// ---------------------------------------------------------------------------
__global__ __launch_bounds__(256) void attn_kernel(
    const short* __restrict__ Qb, const short* __restrict__ Kb,
    const short* __restrict__ VbT, const unsigned long long* __restrict__ Mp,
    short* __restrict__ Ctx) {
  __shared__ short Ks[2][64 * 64];    // [key][d], 16B-chunk c ^= key&7
  __shared__ short Vt[2][64 * 64];    // [d][key], chunk c ^= d&7
  __shared__ short Ps[4 * 16 * 64];   // per-wave [q][key], chunk c ^= q&7
  int qt = blockIdx.x, bh = blockIdx.y;
  int b = bh >> 4, h = bh & 15;
  int q0 = qt * 64;
  int t = threadIdx.x, wid = t >> 6, lane = t & 63;
  int lr = lane & 15, lg = lane >> 4;
  int lr7 = lr & 7;

  const short* Qrow = Qb + ((size_t)bh * SEQ + q0 + wid * 16 + lr) * DHEAD;
  s16x8 qf[2];
  qf[0] = *(const s16x8*)(Qrow + lg * 8);
  qf[1] = *(const s16x8*)(Qrow + 32 + lg * 8);

  const short* KbB = Kb + (size_t)bh * SEQ * DHEAD;    // [key][d]
  const short* VtB = VbT + (size_t)bh * DHEAD * SEQ;   // [d][key]

  // glLDS: HW dest = wave-uniform base + lane*16B -> row=rbase+(l>>3), c=l&7.
  // Pre-swizzled source chunk gives LDS[row][c] = G[row][c ^ (row&7)].
  const int srow = lane >> 3;
  const int schunk = ((lane & 7) ^ srow) * 8;

  float m_run = -1e30f, l_run = 0.f;   // per-lane, q = lr
  f32x4 o_acc[4] = {};

  const unsigned long long* mrow =
      Mp + ((size_t)b * SEQ + q0 + wid * 16 + lr) * (SEQ / 64);

#define STAGE(bufi, k0s)                                                      \
  {                                                                           \
    _Pragma("unroll")                                                         \
    for (int i = 0; i < 2; ++i) {                                             \
      int rbase = wid * 16 + i * 8;                                           \
      gload_lds16(KbB + (size_t)((k0s) + rbase + srow) * DHEAD + schunk,      \
                  &Ks[bufi][rbase * 64]);                                     \
      gload_lds16(VtB + (size_t)(rbase + srow) * SEQ + (k0s) + schunk,        \
                  &Vt[bufi][rbase * 64]);                                     \
    }                                                                         \
  }

  unsigned long long mw_cur = mrow[0];
  STAGE(0, 0);
  asm volatile("s_waitcnt vmcnt(0)" ::: "memory");
  __syncthreads();

  int cur = 0;
  for (int kt = 0; kt < SEQ / 64; ++kt) {
    unsigned long long mw_next = 0;
    if (kt + 1 < SEQ / 64) {
      STAGE(cur ^ 1, (kt + 1) * 64);   // async, in flight across compute
      mw_next = mrow[kt + 1];
    }
    const short* KsC = Ks[cur];
    const short* VtC = Vt[cur];

    // S^T = K·Q^T : sfr[nf][r] = S[key = nf*16 + lg*4 + r][q = lr]
    f32x4 sfr[4];
    __builtin_amdgcn_s_setprio(1);
#pragma unroll
    for (int nf = 0; nf < 4; ++nf) {
      int row = nf * 16 + lr;
      s16x8 kf0 = *(const s16x8*)&KsC[row * 64 + ((lg ^ lr7) << 3)];
      s16x8 kf1 = *(const s16x8*)&KsC[row * 64 + (((4 + lg) ^ lr7) << 3)];
      f32x4 c = {};
      c = __builtin_amdgcn_mfma_f32_16x16x32_bf16(kf0, qf[0], c, 0, 0, 0);
      c = __builtin_amdgcn_mfma_f32_16x16x32_bf16(kf1, qf[1], c, 0, 0, 0);
      sfr[nf] = c;
    }
    __builtin_amdgcn_s_setprio(0);

    unsigned w0 = (unsigned)(mw_cur >> (lg * 4));
    unsigned w1 = (unsigned)(mw_cur >> (lg * 4 + 32));
#pragma unroll
    for (int nf = 0; nf < 4; ++nf)
#pragma unroll
      for (int r = 0; r < 4; ++r) {
        unsigned bit = (nf < 2) ? (w0 >> (nf * 16 + r)) : (w1 >> ((nf - 2) * 16 + r));
        if (bit & 1u) sfr[nf][r] = -1e30f;
      }
    float tm = fmaxf(fmaxf(fmaxf(sfr[0][0], sfr[0][1]), fmaxf(sfr[0][2], sfr[0][3])),
                     fmaxf(fmaxf(sfr[1][0], sfr[1][1]), fmaxf(sfr[1][2], sfr[1][3])));
    float tm2 = fmaxf(fmaxf(fmaxf(sfr[2][0], sfr[2][1]), fmaxf(sfr[2][2], sfr[2][3])),
                      fmaxf(fmaxf(sfr[3][0], sfr[3][1]), fmaxf(sfr[3][2], sfr[3][3])));
    tm = fmaxf(tm, tm2);
    tm = fmaxf(tm, __shfl_xor(tm, 16, 64));
    tm = fmaxf(tm, __shfl_xor(tm, 32, 64));

    bool small = __all(tm <= m_run + 8.0f);
    if (!small) {
      float mnew = fmaxf(m_run, tm);
      float scl = __builtin_amdgcn_exp2f(m_run - mnew);
      m_run = mnew;
      l_run *= scl;
      float scl_o[4];
#pragma unroll
      for (int r = 0; r < 4; ++r) scl_o[r] = __shfl(scl, lg * 4 + r, 64);
#pragma unroll
      for (int nf = 0; nf < 4; ++nf)
#pragma unroll
        for (int r = 0; r < 4; ++r) o_acc[nf][r] *= scl_o[r];
    }
    float ps4[4];
#pragma unroll
    for (int nf = 0; nf < 4; ++nf) {
#pragma unroll
      for (int r = 0; r < 4; ++r)
        sfr[nf][r] = __builtin_amdgcn_exp2f(sfr[nf][r] - m_run);
      ps4[nf] = (sfr[nf][0] + sfr[nf][1]) + (sfr[nf][2] + sfr[nf][3]);
    }
    float ps = (ps4[0] + ps4[1]) + (ps4[2] + ps4[3]);
    ps += __shfl_xor(ps, 16, 64);
    ps += __shfl_xor(ps, 32, 64);
    l_run += ps;

    // P -> LDS (wave-private, swizzled), 4 x ds_write_b64
    int psbase = wid * (16 * 64) + lr * 64;
#pragma unroll
    for (int nf = 0; nf < 4; ++nf) {
      s16x4 pk;
#pragma unroll
      for (int r = 0; r < 4; ++r) pk[r] = f2bf(sfr[nf][r]);
      *(s16x4*)&Ps[psbase + ((((2 * nf + (lg >> 1)) ^ lr7) << 3) | ((lg & 1) << 2))] = pk;
    }
    asm volatile("s_waitcnt lgkmcnt(0)" ::: "memory");
    __builtin_amdgcn_sched_barrier(0);

    // PV: O += P·V
    __builtin_amdgcn_s_setprio(1);
#pragma unroll
    for (int ks = 0; ks < 2; ++ks) {
      s16x8 pf = *(const s16x8*)&Ps[psbase + (((ks * 4 + lg) ^ lr7) << 3)];
#pragma unroll
      for (int nf = 0; nf < 4; ++nf) {
        int d = nf * 16 + lr;
        s16x8 vf = *(const s16x8*)&VtC[d * 64 + (((ks * 4 + lg) ^ lr7) << 3)];
        o_acc[nf] = __builtin_amdgcn_mfma_f32_16x16x32_bf16(pf, vf, o_acc[nf], 0, 0, 0);
      }
    }
    __builtin_amdgcn_s_setprio(0);

    asm volatile("s_waitcnt vmcnt(0)" ::: "memory");  // next tile landed
    __syncthreads();                                  // all waves done w/ cur
    cur ^= 1;
    mw_cur = mw_next;
  }
#undef STAGE
  // epilogue: o_acc[nf][r] is q = lg*4+r, d = nf*16+lr
  float l_o[4];
#pragma unroll
  for (int r = 0; r < 4; ++r) l_o[r] = __shfl(l_run, lg * 4 + r, 64);
#pragma unroll
  for (int nf = 0; nf < 4; ++nf)
#pragma unroll
    for (int r = 0; r < 4; ++r) {
      int srow_ = q0 + wid * 16 + lg * 4 + r;
      float val = o_acc[nf][r] / l_o[r];
      Ctx[((size_t)b * SEQ + srow_) * DMODEL + h * DHEAD + nf * 16 + lr] = f2bf(val);
    }
}

// ---------------------------------------------------------------------------
// Output projection: ctx bf16 @ Wo + bo -> fp32 out.  Full m97 structure:
// both operands staged via global_load_lds.  grid (32,8), block 256.
// ---------------------------------------------------------------------------
__global__ __launch_bounds__(256) void proj_out_kernel(
    const short* __restrict__ Ctx, const short* __restrict__ Wot,
    const float* __restrict__ bo, float* __restrict__ Out) {
  __shared__ short As[128][32];
  __shared__ short Bs[128][32];
  int m0 = blockIdx.x * 128, n0 = blockIdx.y * 128;
  int t = threadIdx.x, wid = t >> 6, lane = t & 63;
  int lr = lane & 15, lg = lane >> 4;
  int wr = wid >> 1, wc = wid & 1;
  f32x4 acc[4][4] = {};

  for (int kt = 0; kt < DMODEL / 32; ++kt) {
    int k0 = kt * 32;
    __syncthreads();
#pragma unroll
    for (int i = 0; i < 2; ++i) {
      int c = i * 256 + t;
      size_t lofs = (size_t)((i * 256 + (t & ~63)) << 3);
      gload_lds16(Ctx + (size_t)(m0 + (c >> 2)) * DMODEL + k0 + ((c & 3) << 3),
                  &As[0][0] + lofs);
      gload_lds16(Wot + (size_t)(n0 + (c >> 2)) * DMODEL + k0 + ((c & 3) << 3),
                  &Bs[0][0] + lofs);
    }
    __syncthreads();
    s16x8 afr[4], bfr[4];
#pragma unroll
    for (int mi = 0; mi < 4; ++mi)
      afr[mi] = *(const s16x8*)&As[wr * 64 + mi * 16 + lr][lg * 8];
#pragma unroll
    for (int ni = 0; ni < 4; ++ni)
      bfr[ni] = *(const s16x8*)&Bs[wc * 64 + ni * 16 + lr][lg * 8];
#pragma unroll
    for (int mi = 0; mi < 4; ++mi)
#pragma unroll
      for (int ni = 0; ni < 4; ++ni)
        acc[mi][ni] = __builtin_amdgcn_mfma_f32_16x16x32_bf16(
            afr[mi], bfr[ni], acc[mi][ni], 0, 0, 0);
  }
#pragma unroll
  for (int mi = 0; mi < 4; ++mi)
#pragma unroll
    for (int ni = 0; ni < 4; ++ni) {
      int n = n0 + wc * 64 + ni * 16 + lr;
      float bv_ = bo[n];
#pragma unroll
      for (int r = 0; r < 4; ++r) {
        int m = m0 + wr * 64 + mi * 16 + lg * 4 + r;
        Out[(size_t)m * DMODEL + n] = acc[mi][ni][r] + bv_;
      }
    }
}

// ---------------------------------------------------------------------------
extern "C" void kernel_launch(void* const* d_in, const int* in_sizes, int n_in,
                              void* d_out, int out_size, void* d_ws, size_t ws_size,
                              hipStream_t stream) {
  const float* key_in   = (const float*)d_in[0];
  const float* value_in = (const float*)d_in[1];
  const float* query_in = (const float*)d_in[2];
  const int*   mask     = (const int*)d_in[3];
  const float* Wq = (const float*)d_in[4];
  const float* bq = (const float*)d_in[5];
  const float* Wk = (const float*)d_in[6];
  const float* bk = (const float*)d_in[7];
  const float* Wv = (const float*)d_in[8];
  const float* bv = (const float*)d_in[9];
  const float* Wo = (const float*)d_in[10];
  const float* bo = (const float*)d_in[11];
  float* out = (float*)d_out;

  short* ws = (short*)d_ws;
  const size_t WSZ   = (size_t)DMODEL * DMODEL;
  const size_t QKVSZ = (size_t)BATCH * NHEAD * SEQ * DHEAD;
  short* Wt  = ws;                         // [4][1024][1024] bf16
  short* QKV = ws + 4 * WSZ;
  short* Qb  = QKV;                        // [bh][s][d]
  short* Kb  = QKV + QKVSZ;                // [bh][s][d]
  short* VbT = QKV + 2 * QKVSZ;            // [bh][d][s]  (pre-transposed)
  short* Ctx = QKV + 3 * QKVSZ;
  // Mp overlays the Wq-transposed region (1 MB < 2 MB), written AFTER
  // proj_qkv has consumed Wt[0] (stream-serialized).
  unsigned long long* Mp = (unsigned long long*)ws;

  wtrans_kernel<<<dim3(16, 16, 4), 256, 0, stream>>>(Wq, Wk, Wv, Wo, Wt);
  proj_qkv_kernel<<<dim3(32, 8, 3), 256, 0, stream>>>(
      query_in, key_in, value_in, Wt, bq, bk, bv, QKV);
  mpack_kernel<<<dim3(1024), 256, 0, stream>>>(mask, Mp);
  attn_kernel<<<dim3(32, 32), 256, 0, stream>>>(Qb, Kb, VbT, Mp, Ctx);
  proj_out_kernel<<<dim3(32, 8), 256, 0, stream>>>(Ctx, Wt + 3 * WSZ, bo, out);
}